// Round 1
// baseline (167.249 us; speedup 1.0000x reference)
//
#include <hip/hip_runtime.h>
#include <math.h>

// Problem constants (T=10240, D=64, L=2048)
//   seg0: q rows [0,4096),     k rows [0,2048)      (1 k-chunk of 2048)
//   seg1: q rows [4096,10240), k rows [2048,10240)  (4 k-chunks of 2048)
// s_qk = 1.25 * dot(t1[q], t1[k]);  w_k = 10 * rowsum(t1[k])
// loss = sum_q (sum_k e^{s} w_k) / (sum_k e^{s})

#define T_ROWS 10240
#define DHEAD  64

// ---------------------------------------------------------------- kernel A
// w[row] = 10 * sum_d t1[row, d]. One wave per row (4 rows / 256-thread block).
__global__ void rowsum_kernel(const float* __restrict__ base,
                              float* __restrict__ w) {
    int row  = blockIdx.x * 4 + (threadIdx.x >> 6);
    int lane = threadIdx.x & 63;
    float v = base[row * DHEAD + lane];
    #pragma unroll
    for (int off = 32; off > 0; off >>= 1)
        v += __shfl_down(v, off);
    if (lane == 0) w[row] = 10.0f * v;
}

// ---------------------------------------------------------------- kernel B
// Each block: 64 q rows x one 2048-row k-chunk. Online softmax partials.
// Threads: 256 = 16(tq) x 16(tk). Thread micro-tile: 4 q (tq+16i) x 8 k (tk+16j).
__global__ __launch_bounds__(256)
void attn_partial_kernel(const float* __restrict__ base,
                         const float* __restrict__ w,
                         float* __restrict__ part_out) {
    __shared__ float Qs[64][68];    // pad 68: compute reads conflict-free/2-way
    __shared__ float Ks[128][68];
    __shared__ float Ws[128];

    int bid = blockIdx.x;
    int qbase, kbase, chunk;
    if (bid < 64) {                       // segment 0
        qbase = bid * 64; kbase = 0; chunk = 0;
    } else {                              // segment 1
        int idx = bid - 64;
        qbase = 4096 + (idx >> 2) * 64;
        chunk = idx & 3;
        kbase = 2048 + chunk * 2048;
    }

    int tid = threadIdx.x;
    int tq  = tid >> 4;    // 0..15
    int tk  = tid & 15;    // 0..15

    // stage Q tile (64 x 64 f32), coalesced float4
    #pragma unroll
    for (int rep = 0; rep < 4; ++rep) {
        int fi = tid + rep * 256;          // 0..1023
        int row = fi >> 4, c4 = (fi & 15) << 2;
        *(float4*)&Qs[row][c4] =
            *(const float4*)&base[(qbase + row) * DHEAD + c4];
    }

    float m[4], Z[4], Nm[4];
    #pragma unroll
    for (int i = 0; i < 4; ++i) { m[i] = -INFINITY; Z[i] = 0.f; Nm[i] = 0.f; }

    for (int kt = 0; kt < 16; ++kt) {      // 16 k-tiles of 128 rows
        int k0 = kbase + kt * 128;
        __syncthreads();                   // prev-iter reads done (also covers Q stage)
        #pragma unroll
        for (int rep = 0; rep < 8; ++rep) {
            int fi = tid + rep * 256;      // 0..2047
            int row = fi >> 4, c4 = (fi & 15) << 2;
            *(float4*)&Ks[row][c4] =
                *(const float4*)&base[(k0 + row) * DHEAD + c4];
        }
        if (tid < 128) Ws[tid] = w[k0 + tid];
        __syncthreads();

        float acc[4][8];
        #pragma unroll
        for (int i = 0; i < 4; ++i)
            #pragma unroll
            for (int j = 0; j < 8; ++j) acc[i][j] = 0.f;

        #pragma unroll 4
        for (int dq = 0; dq < 16; ++dq) {
            float4 qv[4], kv[8];
            #pragma unroll
            for (int i = 0; i < 4; ++i)
                qv[i] = *(const float4*)&Qs[tq + 16 * i][dq << 2];
            #pragma unroll
            for (int j = 0; j < 8; ++j)
                kv[j] = *(const float4*)&Ks[tk + 16 * j][dq << 2];
            #pragma unroll
            for (int i = 0; i < 4; ++i)
                #pragma unroll
                for (int j = 0; j < 8; ++j)
                    acc[i][j] += qv[i].x * kv[j].x + qv[i].y * kv[j].y
                               + qv[i].z * kv[j].z + qv[i].w * kv[j].w;
        }

        // online softmax update (per q row i over this thread's 8 k cols)
        #pragma unroll
        for (int i = 0; i < 4; ++i) {
            float s[8];
            #pragma unroll
            for (int j = 0; j < 8; ++j) s[j] = acc[i][j] * 1.25f;
            float tmax = s[0];
            #pragma unroll
            for (int j = 1; j < 8; ++j) tmax = fmaxf(tmax, s[j]);
            float mn = fmaxf(m[i], tmax);
            float scale = __expf(m[i] - mn);      // exp(-inf)=0 first time
            float zadd = 0.f, nadd = 0.f;
            #pragma unroll
            for (int j = 0; j < 8; ++j) {
                float e = __expf(s[j] - mn);
                zadd += e;
                nadd += e * Ws[tk + 16 * j];
            }
            Z[i]  = Z[i]  * scale + zadd;
            Nm[i] = Nm[i] * scale + nadd;
            m[i]  = mn;
        }
    }

    // merge the 16 tk-partials per q row (reuse Ks as scratch: 3072 <= 8704 f32)
    __syncthreads();
    float (*ps)[16][3] = (float (*)[16][3])(&Ks[0][0]);
    #pragma unroll
    for (int i = 0; i < 4; ++i) {
        int qr = tq + 16 * i;
        ps[qr][tk][0] = m[i];
        ps[qr][tk][1] = Z[i];
        ps[qr][tk][2] = Nm[i];
    }
    __syncthreads();
    if (tid < 64) {
        float mm = -INFINITY, zz = 0.f, nn = 0.f;
        #pragma unroll 4
        for (int t = 0; t < 16; ++t) {
            float mc = ps[tid][t][0], zc = ps[tid][t][1], nc = ps[tid][t][2];
            float mn = fmaxf(mm, mc);
            float s0 = __expf(mm - mn), s1 = __expf(mc - mn);
            zz = zz * s0 + zc * s1;
            nn = nn * s0 + nc * s1;
            mm = mn;
        }
        int gq = qbase + tid;
        float* dst = &part_out[(gq * 4 + chunk) * 3];
        dst[0] = mm; dst[1] = zz; dst[2] = nn;
    }
}

// ---------------------------------------------------------------- kernel C
// Combine per-row chunk partials, contrib = numer/Z, reduce, atomicAdd.
__global__ void finalize_kernel(const float* __restrict__ part,
                                float* __restrict__ out) {
    __shared__ float red[256];
    int gq = blockIdx.x * 256 + threadIdx.x;
    float contrib = 0.f;
    if (gq < T_ROWS) {
        int nch = (gq < 4096) ? 1 : 4;
        float mm = -INFINITY, zz = 0.f, nn = 0.f;
        for (int c = 0; c < nch; ++c) {
            const float* p = &part[(gq * 4 + c) * 3];
            float mc = p[0], zc = p[1], nc = p[2];
            float mn = fmaxf(mm, mc);
            float s0 = __expf(mm - mn), s1 = __expf(mc - mn);
            zz = zz * s0 + zc * s1;
            nn = nn * s0 + nc * s1;
            mm = mn;
        }
        contrib = nn / zz;
    }
    red[threadIdx.x] = contrib;
    __syncthreads();
    #pragma unroll
    for (int s = 128; s > 0; s >>= 1) {
        if (threadIdx.x < s) red[threadIdx.x] += red[threadIdx.x + s];
        __syncthreads();
    }
    if (threadIdx.x == 0) atomicAdd(out, red[0]);
}

// ----------------------------------------------------------------- launch
extern "C" void kernel_launch(void* const* d_in, const int* in_sizes, int n_in,
                              void* d_out, int out_size, void* d_ws, size_t ws_size,
                              hipStream_t stream) {
    const float* base = (const float*)d_in[0];
    float* out = (float*)d_out;
    float* ws  = (float*)d_ws;

    float* w    = ws;             // 10240 floats
    float* part = ws + T_ROWS;    // 10240*4*3 floats (m, Z, numer per row/chunk)

    hipMemsetAsync(d_out, 0, sizeof(float), stream);

    rowsum_kernel<<<T_ROWS / 4, 256, 0, stream>>>(base, w);

    // seg0: 64 q-tiles x 1 chunk; seg1: 96 q-tiles x 4 chunks -> 448 blocks
    attn_partial_kernel<<<448, 256, 0, stream>>>(base, w, part);

    finalize_kernel<<<T_ROWS / 256, 256, 0, stream>>>(part, out);
}

// Round 2
// 51.942 us; speedup vs baseline: 3.2199x; 3.2199x over previous
//
#include <hip/hip_runtime.h>
#include <math.h>

// loss = sum_q softmax-weighted avg of w_k, per ragged segment.
//   s_qk = 1.25 * dot(t1[q], t1[k])   (10x on K and 1/sqrt(64) folded)
//   w_k  = 10 * rowsum(t1[k])
// seg0: q [0,4096),     k [0,2048)
// seg1: q [4096,10240), k [2048,10240)
// Scores via bf16 hi/lo split MFMA (3 products), swapped operands (S^T = K*Q^T)
// so softmax reduction over k is lane-local.

#define T_ROWS 10240
#define DHEAD  64

typedef __bf16 bf16x8 __attribute__((ext_vector_type(8)));
typedef float  f32x16 __attribute__((ext_vector_type(16)));
typedef float  f32x4v __attribute__((ext_vector_type(4)));

// ---------------------------------------------------------------- kernel A
__global__ void rowsum_kernel(const float* __restrict__ base,
                              float* __restrict__ w) {
    int row  = blockIdx.x * 4 + (threadIdx.x >> 6);
    int lane = threadIdx.x & 63;
    float v = base[row * DHEAD + lane];
    #pragma unroll
    for (int off = 32; off > 0; off >>= 1)
        v += __shfl_down(v, off);
    if (lane == 0) w[row] = 10.0f * v;
}

// ---------------------------------------------------------------- staging
struct Staged { f32x4v a0, a1, b0, b1; };

__device__ inline Staged stage_load(const float* __restrict__ base,
                                    int kbase, int t, int row, int g) {
    // unit A: ksub 0 (rows kbase + t*32 + row), unit B: ksub 1 (+1024 rows)
    const float* p0 = base + (size_t)(kbase + t * 32 + row) * DHEAD + g * 8;
    Staged s;
    s.a0 = *(const f32x4v*)p0;
    s.a1 = *(const f32x4v*)(p0 + 4);
    s.b0 = *(const f32x4v*)(p0 + 1024 * DHEAD);
    s.b1 = *(const f32x4v*)(p0 + 1024 * DHEAD + 4);
    return s;
}

__device__ inline void split_store(__bf16* hip_, __bf16* lop_,
                                   f32x4v v0, f32x4v v1) {
    bf16x8 h, l;
    #pragma unroll
    for (int j = 0; j < 4; ++j) {
        __bf16 h0 = (__bf16)v0[j];
        h[j] = h0;
        l[j] = (__bf16)(v0[j] - (float)h0);
        __bf16 h1 = (__bf16)v1[j];
        h[j + 4] = h1;
        l[j + 4] = (__bf16)(v1[j] - (float)h1);
    }
    *(bf16x8*)hip_ = h;
    *(bf16x8*)lop_ = l;
}

// ---------------------------------------------------------------- kernel B
// Block: 256 thr (4 waves). 64 q rows x 2048 k chunk.
// wave wid: q-sub = wid&1 (32 rows), k-sub = wid>>1 (1024 k rows).
__global__ __launch_bounds__(256, 3)
void attn_mfma_kernel(const float* __restrict__ base,
                      const float* __restrict__ w,
                      float* __restrict__ part_out) {
    // K tiles staged as pre-split bf16 hi/lo, double buffered, XOR-swizzled.
    __shared__ __align__(16) __bf16 KhiS[2][2][32 * 64];
    __shared__ __align__(16) __bf16 KloS[2][2][32 * 64];
    __shared__ __align__(16) float  Ws[2048];
    __shared__ float Mg[64][2][3];

    const int tid   = threadIdx.x;
    const int wid   = tid >> 6;
    const int lane  = tid & 63;
    const int l31   = lane & 31;
    const int lhalf = lane >> 5;

    int bid = blockIdx.x;
    int qbase, kbase, chunk;
    if (bid < 64) { qbase = bid * 64; kbase = 0; chunk = 0; }
    else {
        int idx = bid - 64;
        qbase = 4096 + (idx >> 2) * 64;
        chunk = idx & 3;
        kbase = 2048 + chunk * 2048;
    }

    const int qs = wid & 1;
    const int ks = wid >> 1;

    // ---- stage w chunk (2048 f32) into LDS ----
    {
        const float* wsrc = w + kbase + tid * 8;
        *(f32x4v*)&Ws[tid * 8]     = *(const f32x4v*)wsrc;
        *(f32x4v*)&Ws[tid * 8 + 4] = *(const f32x4v*)(wsrc + 4);
    }

    // ---- load this wave's Q rows as scaled hi/lo bf16 fragments ----
    // B-frag (16x32): lane holds col q = lane&31, k-dims (lane>>5)*8 + st*16 ..+7
    bf16x8 qhi[4], qlo[4];
    {
        const float QSCALE = 1.25f;
        const int qrow = qbase + qs * 32 + l31;
        const float* qptr = base + (size_t)qrow * DHEAD + lhalf * 8;
        #pragma unroll
        for (int st = 0; st < 4; ++st) {
            f32x4v a = *(const f32x4v*)(qptr + st * 16);
            f32x4v b = *(const f32x4v*)(qptr + st * 16 + 4);
            #pragma unroll
            for (int j = 0; j < 4; ++j) {
                float v0 = a[j] * QSCALE;
                float v1 = b[j] * QSCALE;
                __bf16 h0 = (__bf16)v0;
                __bf16 h1 = (__bf16)v1;
                qhi[st][j]     = h0;
                qhi[st][j + 4] = h1;
                qlo[st][j]     = (__bf16)(v0 - (float)h0);
                qlo[st][j + 4] = (__bf16)(v1 - (float)h1);
            }
        }
    }

    const int srow = tid >> 3;   // 0..31
    const int sg   = tid & 7;    // 0..7 (16B granule of the 128B bf16 row)
    const int soff = srow * 64 + ((sg ^ (srow & 7)) << 3);

    // prologue: stage tile 0 into buffer 0
    {
        Staged s = stage_load(base, kbase, 0, srow, sg);
        split_store(&KhiS[0][0][soff], &KloS[0][0][soff], s.a0, s.a1);
        split_store(&KhiS[0][1][soff], &KloS[0][1][soff], s.b0, s.b1);
    }
    __syncthreads();

    float m = -INFINITY, Z = 0.f, Nm = 0.f;

    for (int t = 0; t < 32; ++t) {
        const int cur = t & 1;
        const bool pf = (t + 1 < 32);
        Staged pre;
        if (pf) pre = stage_load(base, kbase, t + 1, srow, sg);   // issue early

        // ---- 32k x 32q scores: 12 MFMA (4 K-steps x {hh, hl, lh}) ----
        const __bf16* khiP = &KhiS[cur][ks][0];
        const __bf16* kloP = &KloS[cur][ks][0];
        f32x16 acc0, acc1;
        #pragma unroll
        for (int r = 0; r < 16; ++r) { acc0[r] = 0.f; acc1[r] = 0.f; }
        #pragma unroll
        for (int st = 0; st < 4; ++st) {
            const int off = l31 * 64 + (((st * 2 + lhalf) ^ (l31 & 7)) << 3);
            bf16x8 kh = *(const bf16x8*)(khiP + off);
            bf16x8 kl = *(const bf16x8*)(kloP + off);
            acc0 = __builtin_amdgcn_mfma_f32_32x32x16_bf16(kh, qhi[st], acc0, 0, 0, 0);
            acc1 = __builtin_amdgcn_mfma_f32_32x32x16_bf16(kh, qlo[st], acc1, 0, 0, 0);
            acc1 = __builtin_amdgcn_mfma_f32_32x32x16_bf16(kl, qhi[st], acc1, 0, 0, 0);
        }

        // w for this lane's 16 k rows: k = t*32 + 4*lhalf + 8*(r>>2) + (r&3)
        const int wb = ks * 1024 + t * 32 + 4 * lhalf;
        f32x4v wv[4];
        #pragma unroll
        for (int g = 0; g < 4; ++g)
            wv[g] = *(const f32x4v*)&Ws[wb + 8 * g];

        // ---- online softmax update (lane-local over 16 k) ----
        float s_[16];
        #pragma unroll
        for (int r = 0; r < 16; ++r) s_[r] = acc0[r] + acc1[r];
        float mx[8];
        #pragma unroll
        for (int r = 0; r < 8; ++r) mx[r] = fmaxf(s_[r], s_[r + 8]);
        #pragma unroll
        for (int r = 0; r < 4; ++r) mx[r] = fmaxf(mx[r], mx[r + 4]);
        float tmax = fmaxf(fmaxf(mx[0], mx[1]), fmaxf(mx[2], mx[3]));

        float mn = fmaxf(m, tmax);
        float sc = __expf(m - mn);            // exp(-inf)=0 first tile
        float z0 = 0.f, z1 = 0.f, z2 = 0.f, z3 = 0.f;
        float n0 = 0.f, n1 = 0.f, n2 = 0.f, n3 = 0.f;
        #pragma unroll
        for (int r = 0; r < 16; r += 4) {
            float e0 = __expf(s_[r]     - mn);
            float e1 = __expf(s_[r + 1] - mn);
            float e2 = __expf(s_[r + 2] - mn);
            float e3 = __expf(s_[r + 3] - mn);
            z0 += e0; z1 += e1; z2 += e2; z3 += e3;
            n0 = fmaf(e0, wv[r >> 2][0], n0);
            n1 = fmaf(e1, wv[r >> 2][1], n1);
            n2 = fmaf(e2, wv[r >> 2][2], n2);
            n3 = fmaf(e3, wv[r >> 2][3], n3);
        }
        Z  = fmaf(Z,  sc, (z0 + z1) + (z2 + z3));
        Nm = fmaf(Nm, sc, (n0 + n1) + (n2 + n3));
        m  = mn;

        // ---- commit prefetched tile to the other buffer ----
        if (pf) {
            const int nxt = cur ^ 1;
            split_store(&KhiS[nxt][0][soff], &KloS[nxt][0][soff], pre.a0, pre.a1);
            split_store(&KhiS[nxt][1][soff], &KloS[nxt][1][soff], pre.b0, pre.b1);
        }
        __syncthreads();
    }

    // ---- combine lane l with l^32 (they cover complementary k rows) ----
    {
        float mo = __shfl(m,  lane ^ 32);
        float Zo = __shfl(Z,  lane ^ 32);
        float No = __shfl(Nm, lane ^ 32);
        float mn = fmaxf(m, mo);
        float ea = __expf(m - mn), eb = __expf(mo - mn);
        float Zc = Z * ea + Zo * eb;
        float Nc = Nm * ea + No * eb;
        if (lhalf == 0) {
            Mg[qs * 32 + l31][ks][0] = mn;
            Mg[qs * 32 + l31][ks][1] = Zc;
            Mg[qs * 32 + l31][ks][2] = Nc;
        }
    }
    __syncthreads();

    // ---- combine the two k-subtiles, write chunk partial ----
    if (tid < 64) {
        float ma = Mg[tid][0][0], Za = Mg[tid][0][1], Na = Mg[tid][0][2];
        float mb = Mg[tid][1][0], Zb = Mg[tid][1][1], Nb = Mg[tid][1][2];
        float mn = fmaxf(ma, mb);
        float ea = __expf(ma - mn), eb = __expf(mb - mn);
        float* dst = &part_out[((qbase + tid) * 4 + chunk) * 3];
        dst[0] = mn;
        dst[1] = Za * ea + Zb * eb;
        dst[2] = Na * ea + Nb * eb;
    }
}

// ---------------------------------------------------------------- kernel C
__global__ void finalize_kernel(const float* __restrict__ part,
                                float* __restrict__ out) {
    __shared__ float red[256];
    int gq = blockIdx.x * 256 + threadIdx.x;
    float contrib = 0.f;
    if (gq < T_ROWS) {
        int nch = (gq < 4096) ? 1 : 4;
        float mm = -INFINITY, zz = 0.f, nn = 0.f;
        for (int c = 0; c < nch; ++c) {
            const float* p = &part[(gq * 4 + c) * 3];
            float mc = p[0], zc = p[1], nc = p[2];
            float mn = fmaxf(mm, mc);
            float s0 = __expf(mm - mn), s1 = __expf(mc - mn);
            zz = zz * s0 + zc * s1;
            nn = nn * s0 + nc * s1;
            mm = mn;
        }
        contrib = nn / zz;
    }
    red[threadIdx.x] = contrib;
    __syncthreads();
    #pragma unroll
    for (int s = 128; s > 0; s >>= 1) {
        if (threadIdx.x < s) red[threadIdx.x] += red[threadIdx.x + s];
        __syncthreads();
    }
    if (threadIdx.x == 0) atomicAdd(out, red[0]);
}

// ----------------------------------------------------------------- launch
extern "C" void kernel_launch(void* const* d_in, const int* in_sizes, int n_in,
                              void* d_out, int out_size, void* d_ws, size_t ws_size,
                              hipStream_t stream) {
    const float* base = (const float*)d_in[0];
    float* out = (float*)d_out;
    float* ws  = (float*)d_ws;

    float* w    = ws;             // 10240 floats
    float* part = ws + T_ROWS;    // 10240*4*3 floats

    hipMemsetAsync(d_out, 0, sizeof(float), stream);

    rowsum_kernel<<<T_ROWS / 4, 256, 0, stream>>>(base, w);
    attn_mfma_kernel<<<448, 256, 0, stream>>>(base, w, part);
    finalize_kernel<<<T_ROWS / 256, 256, 0, stream>>>(part, out);
}

// Round 4
// 49.278 us; speedup vs baseline: 3.3940x; 1.0540x over previous
//
#include <hip/hip_runtime.h>
#include <math.h>

// loss = sum_q softmax-weighted avg of w_k, per ragged segment.
//   s2_qk = 1.25*log2(e) * dot(t1[q], t1[k])   (exp2 domain; 10x K + 1/8 folded)
//   w_k   = 10 * rowsum(t1[k])
// seg0: q [0,4096),     k [0,2048)
// seg1: q [4096,10240), k [2048,10240)
// Scores: bf16 hi/lo split MFMA (hh + hl + lh), swapped operands (S^T = K*Q^T).
// K pre-split by prep kernel -> Ksplit[T][128] bf16 (cols 0-63 hi, 64-127 lo),
// staged via global_load_lds with pre-swizzled source (linear LDS dest).
// m seeded with self-score => whole tiles skip softmax via __all().

#define T_ROWS 10240
#define DHEAD  64
#define SCALE2 1.80336880f   // 1.25 * log2(e)
#define SKIP_THR 35.0f

typedef __bf16 bf16x8 __attribute__((ext_vector_type(8)));
typedef float  f32x16 __attribute__((ext_vector_type(16)));
typedef float  f32x4v __attribute__((ext_vector_type(4)));

// hardware exp2: v_exp_f32 computes 2^x; exp2(-inf) = 0
__device__ __forceinline__ float ex2(float x) {
    return __builtin_amdgcn_exp2f(x);
}

// ---------------------------------------------------------------- prep
// Ksplit hi/lo, w = 10*rowsum, selfs = SCALE2*sumsq. 32 rows/block, 8 thr/row.
__global__ __launch_bounds__(256)
void prep_kernel(const float* __restrict__ base, __bf16* __restrict__ ksplit,
                 float* __restrict__ w, float* __restrict__ selfs) {
    int tid = threadIdx.x;
    int row = blockIdx.x * 32 + (tid >> 3);
    int c0  = (tid & 7) << 3;
    const float* p = base + row * DHEAD + c0;
    f32x4v a = *(const f32x4v*)p;
    f32x4v b = *(const f32x4v*)(p + 4);

    float sum = ((a[0] + a[1]) + (a[2] + a[3])) + ((b[0] + b[1]) + (b[2] + b[3]));
    float sq = a[0] * a[0];
    sq = fmaf(a[1], a[1], sq); sq = fmaf(a[2], a[2], sq); sq = fmaf(a[3], a[3], sq);
    sq = fmaf(b[0], b[0], sq); sq = fmaf(b[1], b[1], sq);
    sq = fmaf(b[2], b[2], sq); sq = fmaf(b[3], b[3], sq);
    #pragma unroll
    for (int off = 1; off < 8; off <<= 1) {
        sum += __shfl_xor(sum, off);
        sq  += __shfl_xor(sq, off);
    }
    if ((tid & 7) == 0) { w[row] = 10.0f * sum; selfs[row] = SCALE2 * sq; }

    bf16x8 h, l;
    #pragma unroll
    for (int j = 0; j < 4; ++j) {
        __bf16 h0 = (__bf16)a[j];
        h[j] = h0; l[j] = (__bf16)(a[j] - (float)h0);
        __bf16 h1 = (__bf16)b[j];
        h[j + 4] = h1; l[j + 4] = (__bf16)(b[j] - (float)h1);
    }
    *(bf16x8*)(ksplit + (size_t)row * 128 + c0)      = h;
    *(bf16x8*)(ksplit + (size_t)row * 128 + 64 + c0) = l;
}

// ---------------------------------------------------------------- attn
// Block: 4 waves. 64 q x 2048 k. wave: qs = wid&1 (32 q), ks = wid>>1 (1024 k).
__global__ __launch_bounds__(256, 3)
void attn_mfma_kernel(const float* __restrict__ base,
                      const __bf16* __restrict__ ksplit,
                      const float* __restrict__ w,
                      const float* __restrict__ selfs,
                      float* __restrict__ part_out) {
    // KS[buf][ksub]: 32 rows x 128 bf16 (hi|lo), granule-swizzled by row&7
    __shared__ __align__(16) __bf16 KS[2][2][32 * 128];
    __shared__ __align__(16) float  Ws[2048];
    __shared__ float Mg[64][2][3];

    const int tid   = threadIdx.x;
    const int wid   = tid >> 6;
    const int lane  = tid & 63;
    const int l31   = lane & 31;
    const int lhalf = lane >> 5;

    int bid = blockIdx.x, qbase, kbase, chunk;
    if (bid < 64) { qbase = bid * 64; kbase = 0; chunk = 0; }
    else {
        int idx = bid - 64;
        qbase = 4096 + (idx >> 2) * 64;
        chunk = idx & 3;
        kbase = 2048 + chunk * 2048;
    }
    const int qs = wid & 1, ks = wid >> 1;

    // stage w chunk
    {
        const float* wsrc = w + kbase + tid * 8;
        *(f32x4v*)&Ws[tid * 8]     = *(const f32x4v*)wsrc;
        *(f32x4v*)&Ws[tid * 8 + 4] = *(const f32x4v*)(wsrc + 4);
    }

    // Q fragments (scaled by SCALE2, hi/lo split in regs)
    bf16x8 qhi[4], qlo[4];
    const int qrow = qbase + qs * 32 + l31;
    {
        const float* qptr = base + (size_t)qrow * DHEAD + lhalf * 8;
        #pragma unroll
        for (int st = 0; st < 4; ++st) {
            f32x4v a = *(const f32x4v*)(qptr + st * 16);
            f32x4v b = *(const f32x4v*)(qptr + st * 16 + 4);
            #pragma unroll
            for (int j = 0; j < 4; ++j) {
                float v0 = a[j] * SCALE2, v1 = b[j] * SCALE2;
                __bf16 h0 = (__bf16)v0, h1 = (__bf16)v1;
                qhi[st][j]     = h0;
                qhi[st][j + 4] = h1;
                qlo[st][j]     = (__bf16)(v0 - (float)h0);
                qlo[st][j + 4] = (__bf16)(v1 - (float)h1);
            }
        }
    }

    // m seeded with self-score when row q is inside this segment's k-range
    float m = selfs[qrow];
    if (qbase < 4096 && qrow >= 2048) m = -INFINITY;   // seg0 rows without self
    float Z = 0.f, Nm = 0.f;

    // staging: 16 x 1KB wave-issues per tile; this wave owns fi = wid*4+ii.
    // LDS linear dest; source granule pre-swizzled: slot gsl <- granule gsl^(row&7).
    const __bf16* gsrc[4];
    int ksub_[4], ibuf_[4];
    #pragma unroll
    for (int ii = 0; ii < 4; ++ii) {
        int fi   = wid * 4 + ii;
        int ksub = fi >> 3, ibuf = fi & 7;
        int row  = ibuf * 4 + (lane >> 4);
        int gsl  = lane & 15;
        int g    = gsl ^ (row & 7);
        gsrc[ii] = ksplit + (size_t)(kbase + ksub * 1024 + row) * 128 + g * 8;
        ksub_[ii] = ksub; ibuf_[ii] = ibuf;
    }
    auto stage = [&](int buf, int t) {
        #pragma unroll
        for (int ii = 0; ii < 4; ++ii) {
            __builtin_amdgcn_global_load_lds(
                (const void*)(gsrc[ii] + (size_t)t * (32 * 128)),
                (void*)&KS[buf][ksub_[ii]][ibuf_[ii] * 512],
                16, 0, 0);
        }
    };

    stage(0, 0);
    __syncthreads();   // barrier drains vmcnt(0): tile 0 staged

    for (int t = 0; t < 32; ++t) {
        const int cur = t & 1;
        if (t + 1 < 32) stage(cur ^ 1, t + 1);   // issue early; drained at barrier

        // ---- scores: 12 MFMA (4 K-steps x {hh, hl, lh}) ----
        const __bf16* kp = &KS[cur][ks][0];
        f32x16 acc0, acc1;
        #pragma unroll
        for (int r = 0; r < 16; ++r) { acc0[r] = 0.f; acc1[r] = 0.f; }
        #pragma unroll
        for (int st = 0; st < 4; ++st) {
            const int off = l31 * 128 + (((st * 2 + lhalf) ^ (l31 & 7)) << 3);
            bf16x8 kh = *(const bf16x8*)(kp + off);
            bf16x8 kl = *(const bf16x8*)(kp + off + 64);
            acc0 = __builtin_amdgcn_mfma_f32_32x32x16_bf16(kh, qhi[st], acc0, 0, 0, 0);
            acc1 = __builtin_amdgcn_mfma_f32_32x32x16_bf16(kh, qlo[st], acc1, 0, 0, 0);
            acc1 = __builtin_amdgcn_mfma_f32_32x32x16_bf16(kl, qhi[st], acc1, 0, 0, 0);
        }

        // ---- cheap skip test on acc0 (|acc1| << 1; margin inside SKIP_THR) ----
        float h0 = fmaxf(fmaxf(acc0[0],  acc0[1]),  fmaxf(acc0[2],  acc0[3]));
        float h1 = fmaxf(fmaxf(acc0[4],  acc0[5]),  fmaxf(acc0[6],  acc0[7]));
        float h2 = fmaxf(fmaxf(acc0[8],  acc0[9]),  fmaxf(acc0[10], acc0[11]));
        float h3 = fmaxf(fmaxf(acc0[12], acc0[13]), fmaxf(acc0[14], acc0[15]));
        float hmax = fmaxf(fmaxf(h0, h1), fmaxf(h2, h3));

        if (!__all(hmax <= m - SKIP_THR)) {
            float s_[16];
            #pragma unroll
            for (int r = 0; r < 16; ++r) s_[r] = acc0[r] + acc1[r];
            float mx0 = fmaxf(fmaxf(s_[0], s_[4]), fmaxf(s_[8],  s_[12]));
            float mx1 = fmaxf(fmaxf(s_[1], s_[5]), fmaxf(s_[9],  s_[13]));
            float mx2 = fmaxf(fmaxf(s_[2], s_[6]), fmaxf(s_[10], s_[14]));
            float mx3 = fmaxf(fmaxf(s_[3], s_[7]), fmaxf(s_[11], s_[15]));
            float tmax = fmaxf(fmaxf(mx0, mx1), fmaxf(mx2, mx3));
            float mn = fmaxf(m, tmax);
            float sc = ex2(m - mn);              // exp2(-inf)=0 first time

            const int wb = ks * 1024 + t * 32 + 4 * lhalf;
            f32x4v wv[4];
            #pragma unroll
            for (int g = 0; g < 4; ++g)
                wv[g] = *(const f32x4v*)&Ws[wb + 8 * g];

            float z0 = 0.f, z1 = 0.f, z2 = 0.f, z3 = 0.f;
            float n0 = 0.f, n1 = 0.f, n2 = 0.f, n3 = 0.f;
            #pragma unroll
            for (int g = 0; g < 4; ++g) {
                float e0 = ex2(s_[g * 4]     - mn);
                float e1 = ex2(s_[g * 4 + 1] - mn);
                float e2 = ex2(s_[g * 4 + 2] - mn);
                float e3 = ex2(s_[g * 4 + 3] - mn);
                z0 += e0; z1 += e1; z2 += e2; z3 += e3;
                n0 = fmaf(e0, wv[g][0], n0);
                n1 = fmaf(e1, wv[g][1], n1);
                n2 = fmaf(e2, wv[g][2], n2);
                n3 = fmaf(e3, wv[g][3], n3);
            }
            Z  = fmaf(Z,  sc, (z0 + z1) + (z2 + z3));
            Nm = fmaf(Nm, sc, (n0 + n1) + (n2 + n3));
            m  = mn;
        }
        __syncthreads();   // cur reads done by all; next-tile staging drained
    }

    // ---- combine lane l with l^32 (complementary k rows) ----
    {
        float mo = __shfl(m,  lane ^ 32);
        float Zo = __shfl(Z,  lane ^ 32);
        float No = __shfl(Nm, lane ^ 32);
        float mn = fmaxf(m, mo);
        float ea = ex2(m - mn), eb = ex2(mo - mn);
        float Zc = Z * ea + Zo * eb;
        float Nc = Nm * ea + No * eb;
        if (lhalf == 0) {
            Mg[qs * 32 + l31][ks][0] = mn;
            Mg[qs * 32 + l31][ks][1] = Zc;
            Mg[qs * 32 + l31][ks][2] = Nc;
        }
    }
    __syncthreads();

    if (tid < 64) {
        float ma = Mg[tid][0][0], Za = Mg[tid][0][1], Na = Mg[tid][0][2];
        float mb = Mg[tid][1][0], Zb = Mg[tid][1][1], Nb = Mg[tid][1][2];
        float mn = fmaxf(ma, mb);
        float ea = ex2(ma - mn), eb = ex2(mb - mn);
        float* dst = &part_out[((qbase + tid) * 4 + chunk) * 3];
        dst[0] = mn;
        dst[1] = Za * ea + Zb * eb;
        dst[2] = Na * ea + Nb * eb;
    }
}

// ---------------------------------------------------------------- finalize
__global__ void finalize_kernel(const float* __restrict__ part,
                                float* __restrict__ out) {
    __shared__ float red[256];
    int gq = blockIdx.x * 256 + threadIdx.x;
    float contrib = 0.f;
    if (gq < T_ROWS) {
        int nch = (gq < 4096) ? 1 : 4;
        float mm = -INFINITY, zz = 0.f, nn = 0.f;
        for (int c = 0; c < nch; ++c) {
            const float* p = &part[(gq * 4 + c) * 3];
            float mc = p[0], zc = p[1], nc = p[2];
            float mn = fmaxf(mm, mc);
            float s0 = ex2(mm - mn), s1 = ex2(mc - mn);
            zz = zz * s0 + zc * s1;
            nn = nn * s0 + nc * s1;
            mm = mn;
        }
        contrib = nn / zz;
    }
    red[threadIdx.x] = contrib;
    __syncthreads();
    #pragma unroll
    for (int s = 128; s > 0; s >>= 1) {
        if (threadIdx.x < s) red[threadIdx.x] += red[threadIdx.x + s];
        __syncthreads();
    }
    if (threadIdx.x == 0) atomicAdd(out, red[0]);
}

// ----------------------------------------------------------------- launch
extern "C" void kernel_launch(void* const* d_in, const int* in_sizes, int n_in,
                              void* d_out, int out_size, void* d_ws, size_t ws_size,
                              hipStream_t stream) {
    const float* base = (const float*)d_in[0];
    float* out = (float*)d_out;
    float* ws  = (float*)d_ws;

    float*  w      = ws;                        // 10240 f32
    float*  selfs  = ws + T_ROWS;               // 10240 f32
    float*  part   = ws + 2 * T_ROWS;           // 10240*4*3 f32
    __bf16* ksplit = (__bf16*)(ws + 2 * T_ROWS + T_ROWS * 12);  // 10240*128 bf16

    (void)hipMemsetAsync(d_out, 0, sizeof(float), stream);

    prep_kernel<<<T_ROWS / 32, 256, 0, stream>>>(base, ksplit, w, selfs);
    attn_mfma_kernel<<<448, 256, 0, stream>>>(base, ksplit, w, selfs, part);
    finalize_kernel<<<T_ROWS / 256, 256, 0, stream>>>(part, out);
}